// Round 7
// baseline (987.445 us; speedup 1.0000x reference)
//
#include <hip/hip_runtime.h>
#include <stdint.h>

#define BB 16
#define CC 64
#define NN 65536
#define QQ 16
#define CAP3 384     // fallback kernel's cap
#define ROTD 1024    // fallback transpose rotation
#define POOLW 16384  // candidate pool words (u32) in reused hist LDS

__device__ __forceinline__ unsigned keyify(float x) {
    unsigned u = __float_as_uint(x);
    return u ^ ((unsigned)((int)u >> 31) | 0x80000000u);
}

__device__ __forceinline__ float unkeyify(unsigned k) {
    unsigned u = (k & 0x80000000u) ? (k ^ 0x80000000u) : ~k;
    return __uint_as_float(u);
}

__device__ __forceinline__ int qswz(int c) {
    return ((c >> 2) ^ ((c & 15) << 2)) & 63;
}

extern __shared__ unsigned dynLds[];

// ================= Fused kernel: one block per (batch, channel-quad) ====================
// Reads x directly (every 16B lane-load covers the block's own 4 channels -> 100% byte
// use, no transpose, no workspace). Pass 1: 14-bit hist/channel in 128KB dynamic LDS.
// Resolve top-14 of 128 ranks. Reuse LDS: 64KB u8 live-bin lookup + 64KB u32 pool.
// Pass 2: collect low-18 candidates at exact per-group offsets. Exact select 8+8+2 bits.
__global__ __launch_bounds__(1024) void qsel4(const float* __restrict__ x,
                                              float* __restrict__ out) {
    unsigned* W = dynLds;               // pass 1: [pair][16384] u32 (u16 halves = ch&1)
    unsigned* pool = dynLds + 16384;    // phase B: candidate pool (u32, low-18 bits)

    __shared__ unsigned partial[1024];
    __shared__ unsigned waveOff[16];
    __shared__ unsigned slotRes[128];   // slot s = ch*32 + 2*q + (0 lo | 1 hi)
    __shared__ unsigned slotBin[128];
    __shared__ unsigned slotKey[128];
    __shared__ unsigned liveCnt[128];   // group id = ch*32 + local (holes = 0)
    __shared__ unsigned liveBin[128];
    __shared__ unsigned gbase[128];
    __shared__ unsigned gcnt[128];
    __shared__ uint8_t  gOf[128];

    const int tid  = threadIdx.x;
    const int lane = tid & 63;
    const int wave = tid >> 6;

    // bid remap: co-locate the 4 sibling blocks sharing 64B lines on one XCD (bid%8 hint)
    int bid = blockIdx.x;
    int xcd = bid & 7, q8 = bid >> 3;          // q8 0..31
    int t4 = q8 & 3, sidx = q8 >> 2;           // sidx 0..7
    int set_id = sidx * 8 + xcd;               // 0..63 (b, line-group)
    int b  = set_id >> 2;
    int cq = (set_id & 3) * 4 + t4;            // channel quad 0..15

    const float4* x4 = (const float4*)x + (size_t)b * NN * 16 + cq;   // [n*16]

    for (int i = tid; i < 32768; i += 1024) dynLds[i] = 0;
    if (tid < 128) {
        int i2 = tid & 31;
        int qi = i2 >> 1;
        float idxf = ((float)(qi + 1) * (1.0f / 17.0f)) * 65535.0f;
        int lo = (int)floorf(idxf);
        int hi = (int)ceilf(idxf);
        slotRes[tid] = (unsigned)((i2 & 1) ? hi : lo);
        liveCnt[tid] = 0;
        gcnt[tid] = 0;
    }
    __syncthreads();

    // ---- pass 1: 14-bit histogram per channel ----
    for (int j0 = 0; j0 < 64; j0 += 4) {
        float4 va = x4[(size_t)((j0 + 0) * 1024 + tid) * 16];
        float4 vb = x4[(size_t)((j0 + 1) * 1024 + tid) * 16];
        float4 vc = x4[(size_t)((j0 + 2) * 1024 + tid) * 16];
        float4 vd = x4[(size_t)((j0 + 3) * 1024 + tid) * 16];
#define H1(v) do { \
        atomicAdd(&W[keyify((v).x) >> 18], 1u); \
        atomicAdd(&W[keyify((v).y) >> 18], 1u << 16); \
        atomicAdd(&W[16384 + (keyify((v).z) >> 18)], 1u); \
        atomicAdd(&W[16384 + (keyify((v).w) >> 18)], 1u << 16); } while (0)
        H1(va); H1(vb); H1(vc); H1(vd);
#undef H1
    }
    __syncthreads();

    // ---- resolve top 14 bits, channel by channel (reusing partial[]) ----
    for (int ch = 0; ch < 4; ++ch) {
        const unsigned pbase = (unsigned)(ch >> 1) * 16384;
        const int hsh = (ch & 1) * 16;

        unsigned ssum = 0;
        {
            const unsigned p0 = pbase + (unsigned)tid * 16;
#pragma unroll
            for (int k = 0; k < 16; ++k) {
                unsigned w = W[p0 + ((k + (lane >> 1)) & 15)];
                ssum += (w >> hsh) & 0xFFFFu;
            }
        }
        unsigned incl = ssum;
        for (int off = 1; off < 64; off <<= 1) {
            unsigned t = __shfl_up(incl, off);
            if (lane >= off) incl += t;
        }
        if (lane == 63) waveOff[wave] = incl;
        partial[tid] = incl - ssum;
        __syncthreads();
        if (wave == 0) {
            unsigned w16 = (lane < 16) ? waveOff[lane] : 0u;
            unsigned i16 = w16;
            for (int off = 1; off < 16; off <<= 1) {
                unsigned t = __shfl_up(i16, off);
                if (lane >= off) i16 += t;
            }
            if (lane < 16) waveOff[lane] = i16 - w16;
        }
        __syncthreads();
        partial[tid] += waveOff[wave];
        __syncthreads();

        for (int si = 0; si < 2; ++si) {
            int s = ch * 32 + wave * 2 + si;
            unsigned r = slotRes[s];
            unsigned c = 0;
            const unsigned baseP = (unsigned)lane * 16;
#pragma unroll
            for (int k = 0; k < 16; ++k)
                c += (partial[baseP + ((k + (lane >> 1)) & 15)] <= r) ? 1u : 0u;
            for (int off = 1; off < 64; off <<= 1) c += __shfl_xor(c, off);
            int tstar = (int)c - 1;
            unsigned rr = r - partial[tstar];

            unsigned cntv = 0;
            if (lane < 16) {
                unsigned w = W[pbase + (unsigned)tstar * 16 + lane];
                cntv = (w >> hsh) & 0xFFFFu;
            }
            unsigned incl2 = cntv;
            for (int off = 1; off < 64; off <<= 1) {
                unsigned t = __shfl_up(incl2, off);
                if (lane >= off) incl2 += t;
            }
            unsigned cumStart = incl2 - cntv;
            unsigned long long m = __ballot((lane < 16) && (cumStart <= rr));
            int g = 63 - __clzll(m);
            if (lane == g) {
                unsigned bin = (unsigned)tstar * 16 + (unsigned)g;
                slotBin[s] = bin;
                slotRes[s] = rr - cumStart;
                slotKey[s] = bin << 18;
            }
        }
        __syncthreads();
    }

    // ---- dedup live bins per channel (waves 0-3); read exact counts from W ----
    if (wave < 4) {
        int ch = wave;
        int s = ch * 32 + lane;
        unsigned bn = (lane < 32) ? slotBin[s] : 0xFFFFFFFFu;
        unsigned prev = __shfl_up(bn, 1);
        bool newf = (lane < 32) && (lane == 0 || bn != prev);
        unsigned long long nm = __ballot(newf);
        if (lane < 32) {
            int gl = (int)__popcll(nm & ((1ULL << (lane + 1)) - 1ULL)) - 1;
            gOf[s] = (uint8_t)(ch * 32 + gl);
            if (newf) {
                unsigned w = W[(unsigned)(ch >> 1) * 16384 + bn];
                liveCnt[ch * 32 + gl] = (w >> ((ch & 1) * 16)) & 0xFFFFu;
                liveBin[ch * 32 + gl] = bn;
            }
        }
    }
    __syncthreads();

    // gbase prefix (thread 0); zero L region (first 16384 words) in parallel
    if (tid == 0) {
        unsigned acc = 0;
        for (int g = 0; g < 128; ++g) { gbase[g] = acc; acc += liveCnt[g]; }
    }
    for (int i = tid; i < 16384; i += 1024) dynLds[i] = 0;
    __syncthreads();
    // mark live (ch,bin) in u8 lookup L[ch][16384] with group+1
    if (tid < 128 && liveCnt[tid]) {
        int ch = tid >> 5;
        unsigned bidx = (unsigned)ch * 16384 + liveBin[tid];
        atomicOr(&dynLds[bidx >> 2], (unsigned)(tid + 1) << ((bidx & 3) * 8));
    }
    __syncthreads();

    // ---- pass 2: collect low-18-bit candidates of live bins ----
    for (int j0 = 0; j0 < 64; j0 += 4) {
        float4 va = x4[(size_t)((j0 + 0) * 1024 + tid) * 16];
        float4 vb = x4[(size_t)((j0 + 1) * 1024 + tid) * 16];
        float4 vc = x4[(size_t)((j0 + 2) * 1024 + tid) * 16];
        float4 vd = x4[(size_t)((j0 + 3) * 1024 + tid) * 16];
#define C2(val, chn) do { \
        unsigned kk = keyify(val); \
        unsigned bidx = (unsigned)(chn) * 16384u + (kk >> 18); \
        unsigned mm = (dynLds[bidx >> 2] >> ((bidx & 3) * 8)) & 255u; \
        if (mm) { unsigned gg = mm - 1u; \
            unsigned pp = atomicAdd(&gcnt[gg], 1u); \
            unsigned ix = gbase[gg] + pp; \
            if (ix < (unsigned)POOLW) pool[ix] = kk & 0x3FFFFu; } } while (0)
        C2(va.x, 0); C2(va.y, 1); C2(va.z, 2); C2(va.w, 3);
        C2(vb.x, 0); C2(vb.y, 1); C2(vb.z, 2); C2(vb.w, 3);
        C2(vc.x, 0); C2(vc.y, 1); C2(vc.z, 2); C2(vc.w, 3);
        C2(vd.x, 0); C2(vd.y, 1); C2(vd.z, 2); C2(vd.w, 3);
#undef C2
    }
    __syncthreads();

    // ---- exact select of low 18 bits: 8 slots per wave, stages 8+8+2 ----
    for (int s = wave; s < 128; s += 16) {
        unsigned g = gOf[s];
        unsigned n = liveCnt[g];
        unsigned base = gbase[g];
        if (base >= (unsigned)POOLW) n = 0;
        else if (base + n > (unsigned)POOLW) n = (unsigned)POOLW - base;
        unsigned r = slotRes[s];
        const unsigned* cd = pool + base;

        // stage A: bits [17:10]
        unsigned h0 = 0, h1 = 0, h2 = 0, h3 = 0;
        for (unsigned i = 0; i < n; ++i) {
            unsigned bhi = cd[i] >> 10;
            if ((bhi >> 2) == (unsigned)lane) {
                h0 += (bhi & 3u) == 0u; h1 += (bhi & 3u) == 1u;
                h2 += (bhi & 3u) == 2u; h3 += (bhi & 3u) == 3u;
            }
        }
        unsigned sum4 = h0 + h1 + h2 + h3, incl = sum4;
#pragma unroll
        for (int off = 1; off < 64; off <<= 1) {
            unsigned t = __shfl_up(incl, off);
            if (lane >= off) incl += t;
        }
        unsigned cumStart = incl - sum4;
        unsigned long long m = __ballot(cumStart <= r);
        int gl = 63 - __clzll(m);
        unsigned byteA = 0, r2 = 0;
        if (lane == gl) {
            unsigned cum = cumStart; int jj = 0;
            if (cum + h0 <= r) { cum += h0; jj = 1;
                if (cum + h1 <= r) { cum += h1; jj = 2;
                    if (cum + h2 <= r) { cum += h2; jj = 3; } } }
            byteA = (unsigned)(lane * 4 + jj);
            r2 = r - cum;
        }
        byteA = __shfl(byteA, gl);
        r2    = __shfl(r2, gl);

        // stage B: bits [9:2]
        unsigned k0 = 0, k1 = 0, k2 = 0, k3 = 0;
        for (unsigned i = 0; i < n; ++i) {
            unsigned v = cd[i];
            if ((v >> 10) == byteA) {
                unsigned b2 = (v >> 2) & 255u;
                if ((b2 >> 2) == (unsigned)lane) {
                    k0 += (b2 & 3u) == 0u; k1 += (b2 & 3u) == 1u;
                    k2 += (b2 & 3u) == 2u; k3 += (b2 & 3u) == 3u;
                }
            }
        }
        sum4 = k0 + k1 + k2 + k3; incl = sum4;
#pragma unroll
        for (int off = 1; off < 64; off <<= 1) {
            unsigned t = __shfl_up(incl, off);
            if (lane >= off) incl += t;
        }
        cumStart = incl - sum4;
        m = __ballot(cumStart <= r2);
        gl = 63 - __clzll(m);
        unsigned byteB = 0, r3 = 0;
        if (lane == gl) {
            unsigned cum = cumStart; int jj = 0;
            if (cum + k0 <= r2) { cum += k0; jj = 1;
                if (cum + k1 <= r2) { cum += k1; jj = 2;
                    if (cum + k2 <= r2) { cum += k2; jj = 3; } } }
            byteB = (unsigned)(lane * 4 + jj);
            r3 = r2 - cum;
        }
        byteB = __shfl(byteB, gl);
        r3    = __shfl(r3, gl);

        // stage C: bits [1:0] (per-lane strided scan, shfl reduce)
        unsigned c0 = 0, c1 = 0, c2 = 0, c3 = 0;
        unsigned pref = (byteA << 8) | byteB;
        for (unsigned i = lane; i < n; i += 64) {
            unsigned v = cd[i];
            if ((v >> 2) == pref) {
                c0 += (v & 3u) == 0u; c1 += (v & 3u) == 1u;
                c2 += (v & 3u) == 2u; c3 += (v & 3u) == 3u;
            }
        }
        for (int off = 1; off < 64; off <<= 1) {
            c0 += __shfl_xor(c0, off); c1 += __shfl_xor(c1, off);
            c2 += __shfl_xor(c2, off); c3 += __shfl_xor(c3, off);
        }
        unsigned cum = 0; int jj = 0;
        if (cum + c0 <= r3) { cum += c0; jj = 1;
            if (cum + c1 <= r3) { cum += c1; jj = 2;
                if (cum + c2 <= r3) { cum += c2; jj = 3; } } }
        if (lane == 0) slotKey[s] |= (byteA << 10) | (byteB << 2) | (unsigned)jj;
    }
    __syncthreads();

    // ---- epilogue: interpolate, write (B,C,Q) ----
    if (tid < 64) {
        int chl = tid >> 4, q = tid & 15;
        float idxf = ((float)(q + 1) * (1.0f / 17.0f)) * 65535.0f;
        float frac = idxf - floorf(idxf);
        float vlo = unkeyify(slotKey[chl * 32 + 2 * q]);
        float vhi = unkeyify(slotKey[chl * 32 + 2 * q + 1]);
        out[((size_t)b * CC + (cq * 4 + chl)) * QQ + q] = vlo + (vhi - vlo) * frac;
    }
}

// ======================= verified fallback pipeline (round 5/6) ==========================
__global__ __launch_bounds__(1024) void transpose_keyify(const float* __restrict__ x,
                                                         unsigned* __restrict__ xt) {
    __shared__ unsigned tile[64 * 256];
    int bid  = blockIdx.x;
    int b    = bid >> 8;
    int n0   = (bid & 255) << 8;
    int tid  = threadIdx.x;
    int wave = tid >> 6;
    int lane = tid & 63;

    int f  = tid & 15;
    int nl = tid >> 4;
    const float4* src = (const float4*)(x + ((size_t)b * NN + n0) * CC);
#pragma unroll
    for (int r = 0; r < 4; ++r) {
        int n  = nl + r * 64;
        int nq = n >> 2, ni = n & 3;
        float4 v = src[(size_t)n * 16 + f];
        unsigned ky[4] = { keyify(v.x), keyify(v.y), keyify(v.z), keyify(v.w) };
#pragma unroll
        for (int k = 0; k < 4; ++k) {
            int c = f * 4 + k;
            tile[c * 256 + ((nq ^ qswz(c)) << 2) + ni] = ky[k];
        }
    }
    __syncthreads();

    unsigned* dstb = xt + (size_t)b * ((size_t)CC * NN);
#pragma unroll
    for (int r = 0; r < 4; ++r) {
        int c  = wave + r * 16;
        int qs = qswz(c);
        uint4 o = *(const uint4*)&tile[c * 256 + ((lane ^ qs) << 2)];
        int ns = (n0 + lane * 4 + c * ROTD) & (NN - 1);
        *(uint4*)(dstb + (size_t)c * NN + ns) = o;
    }
}

__device__ __forceinline__ void resolve_level(const unsigned* HIST, int nB, int shCur,
                                              unsigned* slotRes, unsigned* slotBucket,
                                              unsigned* slotKey, unsigned* slotByte,
                                              int lane, int wave) {
    for (int bucket = wave; bucket < nB; bucket += 16) {
        unsigned base = (unsigned)bucket * 256 + lane * 4;
        unsigned c0 = HIST[base], c1 = HIST[base + 1], c2 = HIST[base + 2], c3 = HIST[base + 3];
        unsigned sum4 = c0 + c1 + c2 + c3;
        unsigned incl = sum4;
#pragma unroll
        for (int off = 1; off < 64; off <<= 1) {
            unsigned t = __shfl_up(incl, off);
            if (lane >= off) incl += t;
        }
        unsigned cumStart = incl - sum4;
        for (int s = 0; s < 32; ++s) {
            if ((int)slotBucket[s] != bucket) continue;
            unsigned r = slotRes[s];
            unsigned long long m = __ballot(cumStart <= r);
            int g = 63 - __clzll(m);
            if (lane == g) {
                unsigned cum = cumStart;
                int jj = 0;
                if (cum + c0 <= r) { cum += c0; jj = 1;
                    if (cum + c1 <= r) { cum += c1; jj = 2;
                        if (cum + c2 <= r) { cum += c2; jj = 3; } } }
                unsigned byte = (unsigned)(lane * 4 + jj);
                slotByte[s] = byte;
                slotRes[s]  = r - cum;
                slotKey[s] |= byte << shCur;
            }
        }
    }
}

__global__ __launch_bounds__(1024) void radix3p(const unsigned* __restrict__ xt,
                                                float* __restrict__ out) {
    __shared__ unsigned HC[12288];
    __shared__ uint8_t  map1[256];
    __shared__ uint8_t  t2[32 * 256];
    __shared__ unsigned cnt[32];
    __shared__ unsigned slotRes[32], slotBucket[32], slotKey[32], slotByte[32];
    __shared__ uint8_t  gOf[32];
    __shared__ int      nB1Sh;

    const int tid  = threadIdx.x;
    const int lane = tid & 63;
    const int wave = tid >> 6;
    const int bid  = blockIdx.x;
    const uint4* src = (const uint4*)xt + (size_t)bid * (NN / 4);

    if (tid < 32) {
        int i = tid >> 1;
        float idxf = ((float)(i + 1) * (1.0f / 17.0f)) * 65535.0f;
        int lo = (int)floorf(idxf);
        int hi = (int)ceilf(idxf);
        slotRes[tid]    = (unsigned)((tid & 1) ? hi : lo);
        slotBucket[tid] = 0;
        slotKey[tid]    = 0;
    }
    if (tid == 0) nB1Sh = 1;
    if (tid < 256) map1[tid] = 255;
    for (int i = tid; i < 32 * 256; i += 1024) t2[i] = 255;
    if (tid < 1024) HC[tid] = 0;
    __syncthreads();

    {
        unsigned* h = HC + (wave & 3) * 256;
        uint4 v = src[tid];
#pragma unroll
        for (int j = 0; j < 16; ++j) {
            uint4 vn;
            if (j < 15) vn = src[(j + 1) * 1024 + tid];
            atomicAdd(&h[v.x >> 24], 1u); atomicAdd(&h[v.y >> 24], 1u);
            atomicAdd(&h[v.z >> 24], 1u); atomicAdd(&h[v.w >> 24], 1u);
            v = vn;
        }
    }
    __syncthreads();
    if (tid < 256) HC[tid] = HC[tid] + HC[256 + tid] + HC[512 + tid] + HC[768 + tid];
    __syncthreads();

    resolve_level(HC, 1, 24, slotRes, slotBucket, slotKey, slotByte, lane, wave);
    __syncthreads();

    if (wave == 0) {
        int s = lane;
        unsigned by = (s < 32) ? slotByte[s] : 0u;
        unsigned prevp = __shfl_up(by, 1);
        bool newf = (s < 32) && (s == 0 || by != prevp);
        unsigned long long nm = __ballot(newf);
        if (s < 32) {
            int nb = (int)__popcll(nm & ((1ULL << (s + 1)) - 1ULL)) - 1;
            slotBucket[s] = (unsigned)nb;
            if (newf) map1[by] = (uint8_t)nb;
        }
        if (lane == 0) nB1Sh = (int)__popcll(nm);
    }
    for (int i = tid; i < 8192; i += 1024) HC[i] = 0;
    __syncthreads();

    {
        uint4 v = src[tid];
#pragma unroll
        for (int j = 0; j < 16; ++j) {
            uint4 vn;
            if (j < 15) vn = src[(j + 1) * 1024 + tid];
            unsigned bb;
            bb = map1[v.x >> 24]; if (bb != 255u) atomicAdd(&HC[bb * 256 + ((v.x >> 16) & 255u)], 1u);
            bb = map1[v.y >> 24]; if (bb != 255u) atomicAdd(&HC[bb * 256 + ((v.y >> 16) & 255u)], 1u);
            bb = map1[v.z >> 24]; if (bb != 255u) atomicAdd(&HC[bb * 256 + ((v.z >> 16) & 255u)], 1u);
            bb = map1[v.w >> 24]; if (bb != 255u) atomicAdd(&HC[bb * 256 + ((v.w >> 16) & 255u)], 1u);
            v = vn;
        }
    }
    __syncthreads();

    resolve_level(HC, nB1Sh, 16, slotRes, slotBucket, slotKey, slotByte, lane, wave);
    __syncthreads();

    if (wave == 0) {
        int s = lane;
        unsigned pb = (s < 32) ? slotBucket[s] : 0u;
        unsigned by = (s < 32) ? slotByte[s] : 0u;
        unsigned pair  = (pb << 8) | by;
        unsigned prevp = __shfl_up(pair, 1);
        bool newf = (s < 32) && (s == 0 || pair != prevp);
        unsigned long long nm = __ballot(newf);
        if (s < 32) {
            int g = (int)__popcll(nm & ((1ULL << (s + 1)) - 1ULL)) - 1;
            gOf[s] = (uint8_t)g;
            if (newf) t2[pb * 256 + by] = (uint8_t)g;
        }
    }
    if (tid < 32) cnt[tid] = 0;
    __syncthreads();

    {
        uint4 v = src[tid];
#pragma unroll
        for (int j = 0; j < 16; ++j) {
            uint4 vn;
            if (j < 15) vn = src[(j + 1) * 1024 + tid];
            unsigned bb, g, p;
            bb = map1[v.x >> 24];
            if (bb != 255u) { g = t2[bb * 256 + ((v.x >> 16) & 255u)];
                if (g != 255u) { p = atomicAdd(&cnt[g], 1u); if (p < CAP3) HC[g * CAP3 + p] = v.x; } }
            bb = map1[v.y >> 24];
            if (bb != 255u) { g = t2[bb * 256 + ((v.y >> 16) & 255u)];
                if (g != 255u) { p = atomicAdd(&cnt[g], 1u); if (p < CAP3) HC[g * CAP3 + p] = v.y; } }
            bb = map1[v.z >> 24];
            if (bb != 255u) { g = t2[bb * 256 + ((v.z >> 16) & 255u)];
                if (g != 255u) { p = atomicAdd(&cnt[g], 1u); if (p < CAP3) HC[g * CAP3 + p] = v.z; } }
            bb = map1[v.w >> 24];
            if (bb != 255u) { g = t2[bb * 256 + ((v.w >> 16) & 255u)];
                if (g != 255u) { p = atomicAdd(&cnt[g], 1u); if (p < CAP3) HC[g * CAP3 + p] = v.w; } }
            v = vn;
        }
    }
    __syncthreads();

    for (int s = wave; s < 32; s += 16) {
        unsigned g = gOf[s];
        unsigned n = cnt[g]; if (n > CAP3) n = CAP3;
        unsigned r = slotRes[s];
        const unsigned* cd = &HC[g * CAP3];

        unsigned h0 = 0, h1 = 0, h2 = 0, h3 = 0;
        for (unsigned i = 0; i < n; ++i) {
            unsigned b3 = (cd[i] >> 8) & 255u;
            if ((b3 >> 2) == (unsigned)lane) {
                h0 += (b3 & 3u) == 0u; h1 += (b3 & 3u) == 1u;
                h2 += (b3 & 3u) == 2u; h3 += (b3 & 3u) == 3u;
            }
        }
        unsigned sum4 = h0 + h1 + h2 + h3, incl = sum4;
#pragma unroll
        for (int off = 1; off < 64; off <<= 1) {
            unsigned t = __shfl_up(incl, off);
            if (lane >= off) incl += t;
        }
        unsigned cumStart = incl - sum4;
        unsigned long long m = __ballot(cumStart <= r);
        int gl = 63 - __clzll(m);
        unsigned byte3 = 0, r3 = 0;
        if (lane == gl) {
            unsigned cum = cumStart; int jj = 0;
            if (cum + h0 <= r) { cum += h0; jj = 1;
                if (cum + h1 <= r) { cum += h1; jj = 2;
                    if (cum + h2 <= r) { cum += h2; jj = 3; } } }
            byte3 = (unsigned)(lane * 4 + jj);
            r3 = r - cum;
        }
        byte3 = __shfl(byte3, gl);
        r3    = __shfl(r3, gl);

        unsigned k0 = 0, k1 = 0, k2 = 0, k3 = 0;
        for (unsigned i = 0; i < n; ++i) {
            unsigned v = cd[i];
            if (((v >> 8) & 255u) == byte3) {
                unsigned b4 = v & 255u;
                if ((b4 >> 2) == (unsigned)lane) {
                    k0 += (b4 & 3u) == 0u; k1 += (b4 & 3u) == 1u;
                    k2 += (b4 & 3u) == 2u; k3 += (b4 & 3u) == 3u;
                }
            }
        }
        sum4 = k0 + k1 + k2 + k3; incl = sum4;
#pragma unroll
        for (int off = 1; off < 64; off <<= 1) {
            unsigned t = __shfl_up(incl, off);
            if (lane >= off) incl += t;
        }
        cumStart = incl - sum4;
        m = __ballot(cumStart <= r3);
        gl = 63 - __clzll(m);
        unsigned byte4 = 0;
        if (lane == gl) {
            unsigned cum = cumStart; int jj = 0;
            if (cum + k0 <= r3) { cum += k0; jj = 1;
                if (cum + k1 <= r3) { cum += k1; jj = 2;
                    if (cum + k2 <= r3) { cum += k2; jj = 3; } } }
            byte4 = (unsigned)(lane * 4 + jj);
        }
        byte4 = __shfl(byte4, gl);
        if (lane == 0) slotKey[s] |= (byte3 << 8) | byte4;
    }
    __syncthreads();

    if (tid < QQ) {
        float idxf = ((float)(tid + 1) * (1.0f / 17.0f)) * 65535.0f;
        float frac = idxf - floorf(idxf);
        float vlo = unkeyify(slotKey[2 * tid]);
        float vhi = unkeyify(slotKey[2 * tid + 1]);
        out[(size_t)bid * QQ + tid] = vlo + (vhi - vlo) * frac;
    }
}

extern "C" void kernel_launch(void* const* d_in, const int* in_sizes, int n_in,
                              void* d_out, int out_size, void* d_ws, size_t ws_size,
                              hipStream_t stream) {
    const float* x = (const float*)d_in[0];
    float* out = (float*)d_out;
    const size_t need = (size_t)BB * CC * NN * sizeof(unsigned);  // 256 MiB

    static int dynOk = -1;   // one-time attribute set (host call, graph-safe)
    if (dynOk < 0) {
        hipError_t e = hipFuncSetAttribute((const void*)qsel4,
                                           hipFuncAttributeMaxDynamicSharedMemorySize,
                                           131072);
        dynOk = (e == hipSuccess) ? 1 : 0;
    }

    if (dynOk) {
        qsel4<<<256, 1024, 131072, stream>>>(x, out);   // fused: no transpose, no ws
    } else if (ws_size >= need) {
        unsigned* xt = (unsigned*)d_ws;
        transpose_keyify<<<BB * (NN / 256), 1024, 0, stream>>>(x, xt);
        radix3p<<<BB * CC, 1024, 0, stream>>>(xt, out);
    }
}